// Round 2
// baseline (93.416 us; speedup 1.0000x reference)
//
#include <hip/hip_runtime.h>

// HEGN loss: L_reg + bidirectional chamfer(x, y).  B=8, N=M=4096.
// Phase 1 inner loop uses packed fp32 (v_pk_fma_f32): 2 refs per FMA chain.
#define BB 8
#define NN 4096
#define MC 256                    // reference points staged per chunk
#define NP (MC / 2)               // packed ref pairs per chunk
#define NCHUNK (NN / MC)          // 16
#define KPT 4                     // query points per thread -> 1024 blocks
#define TPB 256
#define PTS_PER_BLOCK (TPB * KPT) // 1024
#define NPTS (2 * BB * NN)        // 65536 (both directions)

typedef float v2f __attribute__((ext_vector_type(2)));

// d = a*b + c on both packed halves; one VOP3P instruction.
__device__ __forceinline__ v2f pk_fma(v2f a, v2f b, v2f c) {
  v2f d;
  asm("v_pk_fma_f32 %0, %1, %2, %3" : "=v"(d) : "v"(a), "v"(b), "v"(c));
  return d;
}

// ws layout: partial[c][zb][p]  c in [0,16), zb in [0,16), p in [0,4096) -> 4 MB

__global__ __launch_bounds__(TPB) void chamfer_partial(
    const float* __restrict__ X, const float* __restrict__ Y,
    float* __restrict__ partial, float* __restrict__ out) {
  // Packed SoA: Wx[j2] = (-2*x_{2j2}, -2*x_{2j2+1}), ..., Wn = |ref|^2 pairs.
  __shared__ v2f Wx[NP], Wy[NP], Wz[NP], Wn[NP];
  const int tid = threadIdx.x;
  const int zb  = blockIdx.z;     // (dir<<3) | b
  const int b   = zb & (BB - 1);
  const int dir = zb >> 3;
  const float* pts  = dir ? (Y + b * NN * 3) : (X + b * NN * 3);
  const float* refs = dir ? (X + b * NN * 3) : (Y + b * NN * 3);
  const int c = blockIdx.y;

  // Replaces the 4-byte hipMemsetAsync dispatch. Safe: chamfer_reduce only
  // touches out after this kernel fully completes (stream ordering).
  if (tid == 0 && blockIdx.x == 0 && blockIdx.y == 0 && blockIdx.z == 0)
    *out = 0.0f;

  {
    const int j = c * MC + tid;   // MC == TPB: one staging iteration
    const float a0 = refs[j * 3 + 0];
    const float a1 = refs[j * 3 + 1];
    const float a2 = refs[j * 3 + 2];
    ((float*)Wx)[tid] = -2.0f * a0;
    ((float*)Wy)[tid] = -2.0f * a1;
    ((float*)Wz)[tid] = -2.0f * a2;
    ((float*)Wn)[tid] = a0 * a0 + a1 * a1 + a2 * a2;
  }
  __syncthreads();

  v2f px2[KPT], py2[KPT], pz2[KPT];
  float pn[KPT], m[KPT];
  const int p0 = blockIdx.x * PTS_PER_BLOCK + tid;
#pragma unroll
  for (int k = 0; k < KPT; k++) {
    const int p = p0 + k * TPB;
    const float x = pts[p * 3 + 0];
    const float y = pts[p * 3 + 1];
    const float z = pts[p * 3 + 2];
    px2[k] = (v2f){x, x};
    py2[k] = (v2f){y, y};
    pz2[k] = (v2f){z, z};
    pn[k] = x * x + y * y + z * z;
    m[k] = 1e30f;
  }

  // min over chunk of (|y|^2 - 2 x.y); |x|^2 added after the loop.
  // Body = 4 refs (2 packed pairs) x KPT queries: 6 pk_fma + 3 min per query.
  // Next body's LDS reads are issued one body ahead (latency cover).
#define CHAMFER_BODY(wx0, wx1, wy0, wy1, wz0, wz1, wn0, wn1)                   \
  _Pragma("unroll") for (int k = 0; k < KPT; k++) {                            \
    v2f s0 = pk_fma(pz2[k], wz0, wn0);                                         \
    s0 = pk_fma(py2[k], wy0, s0);                                              \
    s0 = pk_fma(px2[k], wx0, s0);                                              \
    v2f s1 = pk_fma(pz2[k], wz1, wn1);                                         \
    s1 = pk_fma(py2[k], wy1, s1);                                              \
    s1 = pk_fma(px2[k], wx1, s1);                                              \
    m[k] = fminf(m[k], fminf(fminf(s0[0], s0[1]), fminf(s1[0], s1[1])));       \
  }

  v2f wx0 = Wx[0], wx1 = Wx[1], wy0 = Wy[0], wy1 = Wy[1];
  v2f wz0 = Wz[0], wz1 = Wz[1], wn0 = Wn[0], wn1 = Wn[1];
#pragma unroll 2
  for (int j2 = 0; j2 < NP - 2; j2 += 2) {
    const v2f nx0 = Wx[j2 + 2], nx1 = Wx[j2 + 3];
    const v2f ny0 = Wy[j2 + 2], ny1 = Wy[j2 + 3];
    const v2f nz0 = Wz[j2 + 2], nz1 = Wz[j2 + 3];
    const v2f nn0 = Wn[j2 + 2], nn1 = Wn[j2 + 3];
    CHAMFER_BODY(wx0, wx1, wy0, wy1, wz0, wz1, wn0, wn1)
    wx0 = nx0; wx1 = nx1; wy0 = ny0; wy1 = ny1;
    wz0 = nz0; wz1 = nz1; wn0 = nn0; wn1 = nn1;
  }
  CHAMFER_BODY(wx0, wx1, wy0, wy1, wz0, wz1, wn0, wn1)
#undef CHAMFER_BODY

#pragma unroll
  for (int k = 0; k < KPT; k++) {
    const int p = p0 + k * TPB;
    partial[(c * (2 * BB) + zb) * NN + p] = m[k] + pn[k];
  }
}

// Min across chunks, block-sum, 1 atomic per block into out (zeroed by
// chamfer_partial). Block 0 also adds L_reg. 256 blocks x 1 q/thread:
// all 16 chunk loads independent -> latency-bound time minimized.
__global__ __launch_bounds__(256) void chamfer_reduce(
    const float* __restrict__ partial,
    const float* __restrict__ R, const float* __restrict__ S,
    const float* __restrict__ t, const float* __restrict__ Rgt,
    const float* __restrict__ Sgt, const float* __restrict__ tgt,
    float* __restrict__ out) {
  const int tid = threadIdx.x;
  const int q = blockIdx.x * 256 + tid;   // 256 blocks cover NPTS
  float m = 1e30f;
#pragma unroll
  for (int c = 0; c < NCHUNK; c++)
    m = fminf(m, partial[c * NPTS + q]);
  float s = m;
  for (int o = 32; o > 0; o >>= 1) s += __shfl_down(s, o);
  __shared__ float wsum[4];
  if ((tid & 63) == 0) wsum[tid >> 6] = s;
  __syncthreads();
  if (tid == 0) {
    const float bs = wsum[0] + wsum[1] + wsum[2] + wsum[3];
    atomicAdd(out, bs * (1.0f / (float)(BB * NN)));
  }

  if (blockIdx.x == 0) {
    float v = 0.0f;
    if (tid < 72) {                       // R @ R_gt^T - I, squared
      const int b = tid / 9, ik = tid % 9, i = ik / 3, k = ik % 3;
      const float* Rb = R + b * 9;
      const float* Gb = Rgt + b * 9;
      float d = Rb[i * 3 + 0] * Gb[k * 3 + 0] +
                Rb[i * 3 + 1] * Gb[k * 3 + 1] +
                Rb[i * 3 + 2] * Gb[k * 3 + 2];
      d -= (i == k) ? 1.0f : 0.0f;
      v = d * d;
    } else if (tid < 96) {                // (S - S_gt)^2
      const int i = tid - 72;
      const float d = S[i] - Sgt[i];
      v = d * d;
    } else if (tid < 120) {               // (t - t_gt)^2
      const int i = tid - 96;
      const float d = t[i] - tgt[i];
      v = d * d;
    }
    for (int o = 32; o > 0; o >>= 1) v += __shfl_down(v, o);
    __shared__ float rsum[4];
    if ((tid & 63) == 0) rsum[tid >> 6] = v;
    __syncthreads();
    if (tid == 0) atomicAdd(out, rsum[0] + rsum[1] + rsum[2] + rsum[3]);
  }
}

extern "C" void kernel_launch(void* const* d_in, const int* in_sizes, int n_in,
                              void* d_out, int out_size, void* d_ws, size_t ws_size,
                              hipStream_t stream) {
  const float* X   = (const float*)d_in[0];
  const float* Y   = (const float*)d_in[1];
  const float* R   = (const float*)d_in[2];
  const float* S   = (const float*)d_in[3];
  const float* t   = (const float*)d_in[4];
  const float* Rgt = (const float*)d_in[5];
  const float* Sgt = (const float*)d_in[6];
  const float* tgt = (const float*)d_in[7];

  float* partial = (float*)d_ws;
  float* out     = (float*)d_out;

  dim3 gA(NN / PTS_PER_BLOCK, NCHUNK, 2 * BB);   // (4, 16, 16) = 1024 blocks
  chamfer_partial<<<gA, TPB, 0, stream>>>(X, Y, partial, out);

  chamfer_reduce<<<NPTS / 256, 256, 0, stream>>>(partial, R, S, t, Rgt, Sgt, tgt, out);
}